// Round 8
// baseline (192.801 us; speedup 1.0000x reference)
//
#include <hip/hip_runtime.h>
#include <hip/hip_bf16.h>

#define B_ 32
#define S_ 2048
#define D_ 1024
#define H_ 512
#define M_ (B_*S_)   // 65536
#define BM 128
#define BN 128
#define BK 64
#define TILE (BM*BK) // 8192 shorts = 16 KB

typedef __attribute__((ext_vector_type(8))) short short8;
typedef __attribute__((ext_vector_type(4))) float f32x4;

__device__ __forceinline__ unsigned short f2bf(float f){
  return __builtin_bit_cast(unsigned short, __float2bfloat16(f));  // RNE packed cvt
}

__device__ __forceinline__ float fast_tanh(float x){
  return 1.f - 2.f*__builtin_amdgcn_rcpf(__expf(2.f*x) + 1.f);
}

// XOR swizzle for a [128][64] bf16 LDS tile, 16B granularity (0 conflicts, R4-R7).
__device__ __forceinline__ int swz(int row, int kshort){
  return row*BK + ((kshort & 56) ^ ((row&7)<<3)) + (kshort & 7);
}

// ---------------- kernel W: W1 -> bf16 FRAGMENT-MAJOR ----------------------------
// slot g (one per thread): lane=g&63; r=g>>6: kh=r&1, ni=(r>>1)&3, wh=(r>>3)&1,
// kt=(r>>4)&15, bn=r>>8.  W1f[g*8..+8] = bf16(W1[h][k0..k0+8]) where
// h = bn*128+wh*64+ni*16+(lane&15), k0 = kt*64+kh*32+(lane>>4)*8.
// gemm then loads B-fragments coalesced: 16B/lane at slot-uniform base.
__global__ __launch_bounds__(256) void convw_kernel(
    const float* __restrict__ W1, unsigned short* __restrict__ W1f){
  int g = blockIdx.x*256 + threadIdx.x;   // 0..65535
  int lane = g & 63, r = g >> 6;
  int kh = r & 1, ni = (r>>1)&3, wh = (r>>3)&1, kt = (r>>4)&15, bn = r>>8;
  int h  = bn*128 + wh*64 + ni*16 + (lane&15);
  int k0 = kt*64 + kh*32 + (lane>>4)*8;
  const float* src = W1 + (size_t)h*D_ + k0;
  float4 lo = *(const float4*)src;
  float4 hi = *(const float4*)(src+4);
  short8 v;
  v[0]=(short)f2bf(lo.x); v[1]=(short)f2bf(lo.y); v[2]=(short)f2bf(lo.z); v[3]=(short)f2bf(lo.w);
  v[4]=(short)f2bf(hi.x); v[5]=(short)f2bf(hi.y); v[6]=(short)f2bf(hi.z); v[7]=(short)f2bf(hi.w);
  *(short8*)&W1f[(size_t)g*8] = v;
}

// ---------------- kernel 0: qbias (R1 form — measured 9.9 us) --------------------
__global__ __launch_bounds__(256) void qbias_kernel(
    const float* __restrict__ hidden, const float* __restrict__ W2,
    const float* __restrict__ W1b, const float* __restrict__ W2b,
    float* __restrict__ qb){
  int b = blockIdx.x, h0 = blockIdx.y*64;
  int wave = threadIdx.x>>6, lane = threadIdx.x&63;
  const float* q = hidden + (size_t)(B_ + b)*D_;   // hidden[-1]
  for (int i=0;i<16;i++){
    int h = h0 + wave*16 + i;
    const float* w = W2 + (size_t)h*D_;
    float s = 0.f;
    #pragma unroll
    for (int it=0; it<4; ++it){
      int d = it*256 + lane*4;
      const float4 qq = *(const float4*)(q+d);
      const float4 ww = *(const float4*)(w+d);
      s += qq.x*ww.x + qq.y*ww.y + qq.z*ww.z + qq.w*ww.w;
    }
    #pragma unroll
    for (int off=1; off<64; off<<=1) s += __shfl_xor(s, off);
    if (lane==0) qb[b*H_ + h] = s + W1b[h] + W2b[h];
  }
}

// ---------------- kernel 1: fused score GEMM — B in registers, A dbuf LDS --------
// Per K-step: GLOB_B(kt+1)->regs | COMPUTE(kt) | CVT_A(kt+1)->As[p^1] |
// LOAD_A(kt+2) | lgkm | ONE barrier.  No vmcnt(0) in loop; 1-iter runway on A & B.
__global__ __launch_bounds__(256, 2) void score_gemm(
    const float* __restrict__ enc, const unsigned short* __restrict__ W1f,
    const float* __restrict__ qb, const float* __restrict__ Vw,
    float* __restrict__ score_p){
  const int id  = blockIdx.x;
  const int xcd = id & 7;
  const int j   = id >> 3;
  const int bm  = xcd*64 + (j >> 2);    // 4 same-bm blocks on same XCD (R5: -385MB)
  const int bn  = j & 3;
  const int m0 = bm*BM, h0 = bn*BN;
  const int tid = threadIdx.x, lane = tid&63, wave = tid>>6;
  const int wm = (wave>>1)*64, wh = wave&1, wn = wh*64;

  __shared__ __align__(16) unsigned short As[2][TILE];   // 32 KB

  f32x4 acc[4][4];
  #pragma unroll
  for (int i=0;i<4;i++)
    #pragma unroll
    for (int j2=0;j2<4;j2++)
      acc[i][j2] = (f32x4)(0.f);

  float4 aLo[4], aHi[4];
  short8 b0[4][2], b1[4][2];

#define LOAD_A(KT) do{ const int kkx=(KT)*BK; \
  _Pragma("unroll") for (int i=0;i<4;i++){ \
    int c=tid+i*256; int row=c>>3, kc=(c&7)*8; \
    const float4* pa=(const float4*)(enc+(size_t)(m0+row)*D_+kkx+kc); \
    aLo[i]=pa[0]; aHi[i]=pa[1]; } }while(0)

#define CVT_A(P) do{ \
  _Pragma("unroll") for (int i=0;i<4;i++){ \
    int c=tid+i*256; int row=c>>3, kc=(c&7)*8; short8 av; \
    av[0]=(short)f2bf(aLo[i].x); av[1]=(short)f2bf(aLo[i].y); \
    av[2]=(short)f2bf(aLo[i].z); av[3]=(short)f2bf(aLo[i].w); \
    av[4]=(short)f2bf(aHi[i].x); av[5]=(short)f2bf(aHi[i].y); \
    av[6]=(short)f2bf(aHi[i].z); av[7]=(short)f2bf(aHi[i].w); \
    *(short8*)&As[P][swz(row,kc)] = av; } }while(0)

#define GLOB_B(KT, BB) do{ \
  const size_t sb = (size_t)(((bn*16+(KT))*2+wh)*8)*512 + lane*8; \
  _Pragma("unroll") for (int ni=0;ni<4;ni++) \
    _Pragma("unroll") for (int kh=0;kh<2;kh++) \
      BB[ni][kh] = *(const short8*)&W1f[sb + (size_t)(ni*2+kh)*512]; }while(0)

#define COMPUTE(P, BB) do{ \
  _Pragma("unroll") for (int kh=0; kh<2; ++kh){ \
    const int kb = kh*32 + (lane>>4)*8; \
    short8 af[4]; \
    _Pragma("unroll") for (int mi=0;mi<4;mi++){ \
      int row=wm+mi*16+(lane&15); af[mi]=*(const short8*)&As[P][swz(row,kb)]; } \
    _Pragma("unroll") for (int mi=0;mi<4;mi++) \
      _Pragma("unroll") for (int ni=0;ni<4;ni++) \
        acc[mi][ni]=__builtin_amdgcn_mfma_f32_16x16x32_bf16(af[mi],BB[ni][kh],acc[mi][ni],0,0,0); \
  } }while(0)

#define BODY(KT, BC, BN_) do{ \
  GLOB_B((KT)+1, BN_); \
  __builtin_amdgcn_sched_barrier(0); \
  COMPUTE((KT)&1, BC); \
  CVT_A(((KT)+1)&1); \
  LOAD_A((KT)+2); \
  asm volatile("s_waitcnt lgkmcnt(0)" ::: "memory"); \
  __builtin_amdgcn_s_barrier(); }while(0)

  // ---- prologue
  LOAD_A(0);                       // A(0):8
  GLOB_B(0, b0);                   // B(0):8
  CVT_A(0);                        // auto-wait A(0) (vmcnt(8): B(0) stays in flight)
  LOAD_A(1);                       // A(1):8
  asm volatile("s_waitcnt lgkmcnt(0)" ::: "memory");
  __builtin_amdgcn_s_barrier();

  // ---- steady: kt = 0..13, guard-free
  for (int k2=0; k2<7; ++k2){
    BODY(2*k2,   b0, b1);
    BODY(2*k2+1, b1, b0);
  }
  // ---- kt = 14
  GLOB_B(15, b1);
  __builtin_amdgcn_sched_barrier(0);
  COMPUTE(0, b0);
  CVT_A(1);                        // A(15), loaded at kt=13
  asm volatile("s_waitcnt lgkmcnt(0)" ::: "memory");
  __builtin_amdgcn_s_barrier();
  // ---- kt = 15
  COMPUTE(1, b1);

  // ---- epilogue: fast-tanh + V_w reduce -> per-bn partial score ----------------
  const int bidx = m0 >> 11;
  float qv[4], vwv[4];
  #pragma unroll
  for (int ni=0;ni<4;ni++){
    int h = h0 + wn + ni*16 + (lane&15);
    qv[ni]  = qb[bidx*H_ + h];
    vwv[ni] = Vw[h];
  }
  __shared__ float psum[4][BM];
  #pragma unroll
  for (int mi=0;mi<4;mi++){
    #pragma unroll
    for (int r=0;r<4;r++){
      float s = 0.f;
      #pragma unroll
      for (int ni=0;ni<4;ni++) s += fast_tanh(acc[mi][ni][r] + qv[ni]) * vwv[ni];
      s += __shfl_xor(s,1); s += __shfl_xor(s,2);
      s += __shfl_xor(s,4); s += __shfl_xor(s,8);
      if ((lane&15)==0){
        int m = wm + mi*16 + ((lane>>4)<<2) + r;
        psum[wave][m] = s;
      }
    }
  }
  __syncthreads();
  if (tid < BM){
    int w0 = (tid>>6)*2;
    score_p[(size_t)bn*M_ + m0 + tid] = psum[w0][tid] + psum[w0+1][tid];
  }
}

// ---------------- kernel 2: masked softmax over S (sums 4 bn partials) -----------
__global__ __launch_bounds__(256) void softmax_kernel(
    const float* __restrict__ score_p, const int* __restrict__ mask,
    float* __restrict__ attn){
  int b = blockIdx.x, tid = threadIdx.x;
  int wave = tid>>6, lane = tid&63;
  __shared__ float red[8];
  float v[8];
  float mx = -1e30f;
  #pragma unroll
  for (int i=0;i<8;i++){
    int idx = b*S_ + tid + i*256;
    float sc = score_p[idx] + score_p[M_+idx] + score_p[2*M_+idx] + score_p[3*M_+idx];
    v[i] = (mask[idx]==0) ? -1e9f : sc;
    mx = fmaxf(mx, v[i]);
  }
  #pragma unroll
  for (int off=1; off<64; off<<=1) mx = fmaxf(mx, __shfl_xor(mx, off));
  if (lane==0) red[wave] = mx;
  __syncthreads();
  mx = fmaxf(fmaxf(red[0],red[1]), fmaxf(red[2],red[3]));
  float sum = 0.f;
  #pragma unroll
  for (int i=0;i<8;i++){ v[i] = __expf(v[i]-mx); sum += v[i]; }
  #pragma unroll
  for (int off=1; off<64; off<<=1) sum += __shfl_xor(sum, off);
  if (lane==0) red[4+wave] = sum;
  __syncthreads();
  float inv = 1.f/(red[4]+red[5]+red[6]+red[7]);
  #pragma unroll
  for (int i=0;i<8;i++) attn[b*S_ + tid + i*256] = v[i]*inv;
}

// ---------------- kernel 3: context (R5 form — plain loads, 2-way ILP) -----------
__global__ __launch_bounds__(256) void context_kernel(
    const float* __restrict__ enc, const float* __restrict__ attn,
    float* __restrict__ ctx){
  int b = blockIdx.x, sc = blockIdx.y;
  int s0 = sc*64;
  int d4 = threadIdx.x*4;
  const float* ep = enc + ((size_t)b*S_ + s0)*D_ + d4;
  const float* ap = attn + b*S_ + s0;
  float4 a0 = make_float4(0.f,0.f,0.f,0.f);
  float4 a1 = make_float4(0.f,0.f,0.f,0.f);
  #pragma unroll 4
  for (int i=0;i<64;i+=2){
    float w0 = ap[i], w1 = ap[i+1];
    float4 e0 = *(const float4*)(ep + (size_t)i*D_);
    float4 e1 = *(const float4*)(ep + (size_t)(i+1)*D_);
    a0.x = fmaf(w0, e0.x, a0.x); a0.y = fmaf(w0, e0.y, a0.y);
    a0.z = fmaf(w0, e0.z, a0.z); a0.w = fmaf(w0, e0.w, a0.w);
    a1.x = fmaf(w1, e1.x, a1.x); a1.y = fmaf(w1, e1.y, a1.y);
    a1.z = fmaf(w1, e1.z, a1.z); a1.w = fmaf(w1, e1.w, a1.w);
  }
  float* o = ctx + b*D_ + d4;
  atomicAdd(o+0, a0.x+a1.x); atomicAdd(o+1, a0.y+a1.y);
  atomicAdd(o+2, a0.z+a1.z); atomicAdd(o+3, a0.w+a1.w);
}

extern "C" void kernel_launch(void* const* d_in, const int* in_sizes, int n_in,
                              void* d_out, int out_size, void* d_ws, size_t ws_size,
                              hipStream_t stream){
  const float* hidden = (const float*)d_in[0];
  const float* enc    = (const float*)d_in[1];
  const int*   mask   = (const int*)d_in[2];
  const float* W1w    = (const float*)d_in[3];
  const float* W1b    = (const float*)d_in[4];
  const float* W2w    = (const float*)d_in[5];
  const float* W2b    = (const float*)d_in[6];
  const float* Vw     = (const float*)d_in[7];
  // V_b (d_in[8]) provably cancels in softmax — unused.
  float* out = (float*)d_out;

  float* qb           = (float*)d_ws;                      // 64 KB
  float* score_p      = qb + B_*H_;                        // 1 MB
  unsigned short* W1f = (unsigned short*)(score_p + 4*M_); // 1 MB bf16 frag-major

  hipMemsetAsync(out, 0, (size_t)B_*D_*sizeof(float), stream);

  convw_kernel  <<<H_*D_/8/256,     256, 0, stream>>>(W1w, W1f);
  qbias_kernel  <<<dim3(B_, H_/64), 256, 0, stream>>>(hidden, W2w, W1b, W2b, qb);
  score_gemm    <<<4*(M_/BM),       256, 0, stream>>>(enc, W1f, qb, Vw, score_p);
  softmax_kernel<<<B_,              256, 0, stream>>>(score_p, mask, out + B_*D_);
  context_kernel<<<dim3(B_, 32),    256, 0, stream>>>(enc, out + B_*D_, out);
}